// Round 5
// baseline (263.306 us; speedup 1.0000x reference)
//
#include <hip/hip_runtime.h>
#include <hip/hip_bf16.h>

// MyGNN on MI355X — round 10.
//  prep: zero padded counts + W1/Wfi -> frag bf16 + Wc=W2@Wl -> frag bf16 + bc
//  K1 (fused): single-pass WIDE fill (1 edge/thread) ∪ gemm1(x1@W1->t_bf)
//              ∪ branch0(gather x0@Wfi->out)
//  agg1: h1 = A@t1 + b1 (bf16 out)     [single <=32-deep guarded gather exposure]
//  agg2_sel: sel[m] = A-row(node(m)) @ h1   (M rows, bf16 out, no bias)
//  br1: out1 = sel@Wc + bc            [gemm2 eliminated algebraically]
// Round-10 deltas (atomic line-serialization theory):
//  - counts padded to ONE COUNTER PER 64B LINE (counts[d<<4], 4 MB): same-line
//    far-atomic RMW contention 16 -> 1.
//  - bucket slots interleaved across the node row's two 64B lines
//    (pos -> ((pos&1)<<5)|(pos>>1)): per-line store bursts 16 -> 8. Readers
//    apply the same index permutation in their shfl (coalescing unchanged).

#define B_    64
#define ADJ_  1000
#define N_    64000
#define E_    (1 << 20)
#define M_    32000
#define DV    128
#define CAP   64
#define CSH   4                // counts stride shift: 16 ints = 64B per counter
#define CHUNKS 4096
#define EPB   (E_ / CHUNKS)    // 256 edges per fill block = 1/thread

typedef __attribute__((ext_vector_type(8))) short short8v;   // 8 bf16
typedef __attribute__((ext_vector_type(4))) float float4v;

__device__ __forceinline__ float u2f(unsigned int u) {
  union { unsigned int i; float f; } x; x.i = u; return x.f;
}
__device__ __forceinline__ unsigned short f2bf(float f) {   // RNE
  union { float f; unsigned int i; } x; x.f = f;
  unsigned int r = x.i + 0x7fffu + ((x.i >> 16) & 1u);
  return (unsigned short)(r >> 16);
}
__device__ __forceinline__ unsigned int pack_bf2(float a, float b) {
  __hip_bfloat162 h = __float22bfloat162_rn(float2{a, b});
  union { __hip_bfloat162 h; unsigned int u; } c; c.h = h;
  return c.u;
}

// frag addr for W[k][n] (128x128), matches gemm_tile's B-frag read
__device__ __forceinline__ int frag_addr(int k, int n) {
  return ((((n >> 4) * 4 + (k >> 5)) * 64 + ((k >> 3) & 3) * 16 + (n & 15)) << 3)
       + (k & 7);
}

// ---------------- prep: counts=0 + W frags + Wc fold ----------------
// blocks 0-15: W1/Wfi frag convert; 16-31: Wc=W2@Wl fold; 32: bc. Grid 33.
__global__ __launch_bounds__(256)
void prep_k(const float* __restrict__ W1, const float* __restrict__ Wfi,
            const float* __restrict__ W2, const float* __restrict__ Wl,
            const float* __restrict__ b2, const float* __restrict__ bl,
            unsigned short* __restrict__ Wbf, float* __restrict__ bc,
            int* __restrict__ counts) {
  int b = blockIdx.x, t = threadIdx.x;
  if (b < 16) {
    const float* W = (b < 8) ? W1 : Wfi;
    unsigned short* out = Wbf + ((b < 8) ? 0 : 16384);
    int base = (b & 7) * 2048 + t * 8;
    float4 f0 = *(const float4*)(W + base);
    float4 f1 = *(const float4*)(W + base + 4);
    float v[8] = {f0.x, f0.y, f0.z, f0.w, f1.x, f1.y, f1.z, f1.w};
#pragma unroll
    for (int u = 0; u < 8; u++) {
      int g = base + u;
      out[frag_addr(g >> 7, g & 127)] = f2bf(v[u]);
    }
  } else if (b < 32) {
    // Wc[k][n..n+3] = sum_j W2[k][j] * Wl[j][n..n+3]
    unsigned short* out = Wbf + 2 * 16384;
    int g0 = (b - 16) * 1024 + t * 4;
    int k = g0 >> 7, n = g0 & 127;
    float4 acc = {0.f, 0.f, 0.f, 0.f};
    for (int j = 0; j < 128; j++) {
      float w2 = W2[k * 128 + j];
      float4 wl = *(const float4*)(Wl + j * 128 + n);
      acc.x += w2 * wl.x; acc.y += w2 * wl.y;
      acc.z += w2 * wl.z; acc.w += w2 * wl.w;
    }
    out[frag_addr(k, n + 0)] = f2bf(acc.x);
    out[frag_addr(k, n + 1)] = f2bf(acc.y);
    out[frag_addr(k, n + 2)] = f2bf(acc.z);
    out[frag_addr(k, n + 3)] = f2bf(acc.w);
  } else {
    if (t < 128) {
      float acc = bl[t];
      for (int k = 0; k < 128; k++) acc += b2[k] * Wl[k * 128 + t];
      bc[t] = acc;
    }
  }
  // zero padded counts: (N_<<CSH) ints = 4 MB, int4-wide
  int4* cz = (int4*)counts;
  int total4 = (N_ << CSH) >> 2;
  for (int i = b * 256 + t; i < total4; i += 33 * 256) cz[i] = int4{0, 0, 0, 0};
}

// ---------------- single-pass WIDE fill (device fn): chunk c, 1 edge/thread ----------------
__device__ __forceinline__ void fill_once(const int* __restrict__ ei,
                                          int* __restrict__ counts,
                                          unsigned short* __restrict__ bucket,
                                          int c) {
  int e = c * EPB + (int)threadIdx.x;
  int d = ei[E_ + e];                    // dst
  int s = ei[e];                         // src
  int pos = atomicAdd(&counts[d << CSH], 1);   // one counter per 64B line
  if (pos < CAP) {
    int idx = ((pos & 1) << 5) | (pos >> 1);   // interleave across 2 lines
    __hip_atomic_store(&bucket[(size_t)d * CAP + idx], (unsigned short)s,
                       __ATOMIC_RELAXED, __HIP_MEMORY_SCOPE_AGENT);
  }
}

// ---------------- MFMA GEMM tile (device fn) ----------------
// tile = 64 rows; 4 waves x 16-row stripes; B pre-converted frag-ordered bf16.
// Two-half staging: 16 KB LDS; half-1 global loads overlap half-0 MFMAs.
// C/D: col = lane&15, row = (lane>>4)*4 + reg.
template<bool GATHER, bool ABF16, bool OUTBF16, bool HASBIAS>
__device__ __forceinline__ void gemm_tile(const void* __restrict__ in,
                                          const unsigned short* __restrict__ Wbf,
                                          const float* __restrict__ bias,
                                          void* __restrict__ out_, int tile,
                                          const int* __restrict__ bidx,
                                          const int* __restrict__ nidx,
                                          unsigned short* __restrict__ Bs) {
  int tid  = threadIdx.x;
  int lane = tid & 63;
  int wv   = tid >> 6;
  int m    = lane & 15;
  int q    = lane >> 4;
  int rbase = tile * 64 + wv * 16;
  int r     = rbase + m;

  const short8v* Wv  = (const short8v*)Wbf;   // 2048 vecs (32 KB)
  short8v*       Bsv = (short8v*)Bs;          // 1024 vecs (16 KB)

  short8v w[4];
#pragma unroll
  for (int i = 0; i < 4; i++) w[i] = Wv[tid + i * 256];

  size_t ir;
  if (GATHER) ir = (size_t)bidx[r] * ADJ_ + nidx[r];
  else        ir = (size_t)r;

  short8v af[4];
  if (ABF16) {
    const unsigned short* arow = (const unsigned short*)in + ir * DV;
#pragma unroll
    for (int kc = 0; kc < 4; kc++)
      af[kc] = *(const short8v*)(arow + kc * 32 + q * 8);
  } else {
    const float* arow = (const float*)in + ir * DV;
#pragma unroll
    for (int kc = 0; kc < 4; kc++) {
      const float4* p = (const float4*)(arow + kc * 32 + q * 8);
      float4 f0 = p[0], f1 = p[1];
      union { short8v s; unsigned int u[4]; } t;
      t.u[0] = pack_bf2(f0.x, f0.y);
      t.u[1] = pack_bf2(f0.z, f0.w);
      t.u[2] = pack_bf2(f1.x, f1.y);
      t.u[3] = pack_bf2(f1.z, f1.w);
      af[kc] = t.s;
    }
  }

#pragma unroll
  for (int i = 0; i < 4; i++) Bsv[tid + i * 256] = w[i];
  __syncthreads();

  float4v acc[8];
#pragma unroll
  for (int nb = 0; nb < 8; nb++) acc[nb] = (float4v){0.f, 0.f, 0.f, 0.f};

#pragma unroll
  for (int i = 0; i < 4; i++) w[i] = Wv[1024 + tid + i * 256];

#pragma unroll
  for (int nb = 0; nb < 4; nb++)
#pragma unroll
    for (int kc = 0; kc < 4; kc++) {
      short8v bf = Bsv[(nb * 4 + kc) * 64 + lane];
      acc[nb] = __builtin_amdgcn_mfma_f32_16x16x32_bf16(af[kc], bf, acc[nb], 0, 0, 0);
    }
  __syncthreads();
#pragma unroll
  for (int i = 0; i < 4; i++) Bsv[tid + i * 256] = w[i];
  __syncthreads();
#pragma unroll
  for (int nb = 4; nb < 8; nb++)
#pragma unroll
    for (int kc = 0; kc < 4; kc++) {
      short8v bf = Bsv[((nb - 4) * 4 + kc) * 64 + lane];
      acc[nb] = __builtin_amdgcn_mfma_f32_16x16x32_bf16(af[kc], bf, acc[nb], 0, 0, 0);
    }

#pragma unroll
  for (int nb = 0; nb < 8; nb++) {
    float bvn = HASBIAS ? bias[nb * 16 + m] : 0.f;
    int col = nb * 16 + m;
#pragma unroll
    for (int i = 0; i < 4; i++) {
      int row = rbase + q * 4 + i;
      float v = acc[nb][i] + bvn;
      if (OUTBF16) ((unsigned short*)out_)[(size_t)row * DV + col] = f2bf(v);
      else         ((float*)out_)[(size_t)row * DV + col] = v;
    }
  }
}

// ---------------- K1: fused wide fill + gemm1 + branch0 ----------------
// Period-11 blocks: rem 0..7 -> fill chunk g*8+rem (4096 fills); rem 8..10 ->
// o = g*3+rem-8: o<1000 gemm1, o<1500 br0, else idle. Grid 512*11 = 5632.
__global__ __launch_bounds__(256)
void k1_fused(const int* __restrict__ ei, int* __restrict__ counts,
              unsigned short* __restrict__ bucket,
              const float* __restrict__ x1, const unsigned short* __restrict__ Wbf,
              unsigned int* __restrict__ t_bf,
              const float* __restrict__ x0, const float* __restrict__ bfi,
              float* __restrict__ out0,
              const int* __restrict__ b0, const int* __restrict__ n0i) {
  __shared__ unsigned short Bs[8192];   // 16 KB
  int g = blockIdx.x / 11, rem = blockIdx.x % 11;
  if (rem < 8) { fill_once(ei, counts, bucket, g * 8 + rem); return; }
  int o = g * 3 + rem - 8;
  if (o < 1000)
    gemm_tile<false, false, true, false>(x1, Wbf, nullptr, t_bf, o, nullptr, nullptr, Bs);
  else if (o < 1500)
    gemm_tile<true, false, false, true>(x0, Wbf + 16384, bfi, out0, o - 1000, b0, n0i, Bs);
}

// ---------------- standalone GEMM ----------------
template<bool GATHER, bool ABF16, bool OUTBF16, bool HASBIAS>
__global__ __launch_bounds__(256)
void gemm_k(const void* __restrict__ in, const unsigned short* __restrict__ Wbf,
            const float* __restrict__ bias, void* __restrict__ out_,
            const int* __restrict__ bidx, const int* __restrict__ nidx) {
  __shared__ unsigned short Bs[8192];
  gemm_tile<GATHER, ABF16, OUTBF16, HASBIAS>(in, Wbf, bias, out_, blockIdx.x, bidx, nidx, Bs);
}

// ---------------- aggregation: one wave per row, single <=32-deep exposure ----------------
// SEL=false: row w = node id. SEL=true: row w = output slot, node from (bidx,nidx).
// cnt is wave-uniform; per-i `if (i<cnt)` guards are uniform branches. Slot i is
// held by lane ((i&1)<<5)|(i>>1) (writer's 2-line interleave).
template<bool OUTBF16, bool SEL>
__global__ __launch_bounds__(256)
void aggregate_k(const unsigned int* __restrict__ x,   // bf16x2 rows [N,64]
                 const int* __restrict__ counts,
                 const unsigned short* __restrict__ bucket,
                 const float* __restrict__ bias, void* __restrict__ out_,
                 const int* __restrict__ bidx, const int* __restrict__ nidx) {
  int w    = (blockIdx.x * 256 + threadIdx.x) >> 6;
  int lane = threadIdx.x & 63;
  int node = SEL ? (bidx[w] * ADJ_ + nidx[w]) : w;
  int cnt = counts[node << CSH]; cnt = min(cnt, CAP);
  int mysrc = (int)bucket[(size_t)node * CAP + lane];   // lane l holds ushort idx l

  float2 acc;
  if (bias) { float2 bv = ((const float2*)bias)[lane]; acc.x = bv.x; acc.y = bv.y; }
  else      { acc.x = 0.f; acc.y = 0.f; }

  unsigned int uu[32];
#pragma unroll
  for (int i = 0; i < 32; i++)
    if (i < cnt) {                       // wave-uniform guard
      int s = __shfl(mysrc, ((i & 1) << 5) | (i >> 1), 64);
      uu[i] = x[(size_t)s * 64 + lane];
    }
#pragma unroll
  for (int i = 0; i < 32; i++)
    if (i < cnt) {
      acc.x += u2f(uu[i] << 16);
      acc.y += u2f(uu[i] & 0xffff0000u);
    }
  for (int d = 32; d < cnt; d++) {       // rare tail
    int s = __shfl(mysrc, ((d & 1) << 5) | (d >> 1), 64);
    unsigned int u = x[(size_t)s * 64 + lane];
    acc.x += u2f(u << 16);
    acc.y += u2f(u & 0xffff0000u);
  }

  if (OUTBF16) ((unsigned int*)out_)[(size_t)w * 64 + lane] = pack_bf2(acc.x, acc.y);
  else         ((float2*)out_)[(size_t)w * 64 + lane] = acc;
}

extern "C" void kernel_launch(void* const* d_in, const int* in_sizes, int n_in,
                              void* d_out, int out_size, void* d_ws, size_t ws_size,
                              hipStream_t stream) {
  const float* x0  = (const float*)d_in[0];
  const float* x1  = (const float*)d_in[1];
  const int*   ei  = (const int*)  d_in[2];
  const int*   b0  = (const int*)  d_in[3];
  const int*   n0i = (const int*)  d_in[4];
  const int*   b1  = (const int*)  d_in[5];
  const int*   n1i = (const int*)  d_in[6];
  const float* W1  = (const float*)d_in[7];
  const float* bb1 = (const float*)d_in[8];
  const float* W2  = (const float*)d_in[9];
  const float* bb2 = (const float*)d_in[10];
  const float* Wl  = (const float*)d_in[11];
  const float* bl  = (const float*)d_in[12];
  const float* Wfi = (const float*)d_in[13];
  const float* bfi = (const float*)d_in[14];
  float* out = (float*)d_out;

  // ws: t_bf 16MB (sel_bf aliases it) | h_bf 16MB | counts 4MB (padded)
  //     | bucket 8MB | Wbf 96KB | bc 512B   (total ~44.4MB)
  unsigned int*   t_bf   = (unsigned int*)d_ws;
  unsigned int*   sel_bf = t_bf;                        // alias: t1 dead after agg1
  unsigned int*   h_bf   = t_bf + (size_t)N_ * 64;
  int*            counts = (int*)(h_bf + (size_t)N_ * 64);
  unsigned short* bucket = (unsigned short*)(counts + ((size_t)N_ << CSH));
  unsigned short* Wbf    = bucket + (size_t)N_ * CAP;
  float*          bc     = (float*)(Wbf + 3 * 16384);

  // prep: counts=0, W1/Wfi frag, Wc=W2@Wl frag, bc=b2@Wl+bl
  prep_k<<<33, 256, 0, stream>>>(W1, Wfi, W2, Wl, bb2, bl, Wbf, bc, counts);

  // K1: wide single-pass fill ∪ t1=x1@W1 ∪ out0=gather(x0)@Wfi+bfi
  k1_fused<<<5632, 256, 0, stream>>>(ei, counts, bucket, x1, Wbf, t_bf,
                                     x0, bfi, out, b0, n0i);

  // h1 = A@t1 + b1  (bf16 out)
  aggregate_k<true, false><<<N_ / 4, 256, 0, stream>>>(t_bf, counts, bucket,
                                                       bb1, h_bf, nullptr, nullptr);
  // sel[m] = A-row(node(m)) @ h1  (bf16 out, bias folded into bc)
  aggregate_k<true, true><<<M_ / 4, 256, 0, stream>>>(h_bf, counts, bucket,
                                                      nullptr, sel_bf, b1, n1i);
  // out1 = sel@Wc + bc  (f32 out)   [Wc = W2@Wl, bc = b2@Wl + bl]
  gemm_k<false, true, false, true><<<M_ / 64, 256, 0, stream>>>(sel_bf, Wbf + 2 * 16384,
                                                                bc, out + (size_t)M_ * DV,
                                                                nullptr, nullptr);
}

// Round 6
// 256.556 us; speedup vs baseline: 1.0263x; 1.0263x over previous
//
#include <hip/hip_runtime.h>
#include <hip/hip_bf16.h>

// MyGNN on MI355X — round 11.
//  prep: zero counts + W1/Wfi -> frag bf16 + Wc=W2@Wl -> frag bf16 + bc
//  K1 (fused): single-pass WIDE fill (1 edge/thread, device atomicAdd counts,
//              PLAIN write-back bucket stores) ∪ gemm1(x1@W1->t_bf)
//              ∪ branch0(gather x0@Wfi->out)
//  agg1: h1 = A@t1 + b1 (bf16 out)     [single <=32-deep guarded gather exposure]
//  agg2_sel: sel[m] = A-row(node(m)) @ h1   (M rows, bf16 out, no bias)
//  br1: out1 = sel@Wc + bc            [gemm2 eliminated algebraically]
// Round-11 delta (write-through theory): round-10 WRITE_SIZE showed 64MB excess
// = 1M x 64B, i.e. each agent-scope 2B bucket store went write-through as a full
// line. Bucket readers are LATER DISPATCHES, and kernel-boundary release/acquire
// guarantees visibility; cross-XCD disjoint-byte line sharing merges via byte
// dirty masks on writeback. So bucket stores are plain cached stores (L2
// write-combining). Counts padding + slot interleave (both proven neutral in
// round 10) reverted.

#define B_    64
#define ADJ_  1000
#define N_    64000
#define E_    (1 << 20)
#define M_    32000
#define DV    128
#define CAP   64
#define CHUNKS 4096
#define EPB   (E_ / CHUNKS)    // 256 edges per fill block = 1/thread

typedef __attribute__((ext_vector_type(8))) short short8v;   // 8 bf16
typedef __attribute__((ext_vector_type(4))) float float4v;

__device__ __forceinline__ float u2f(unsigned int u) {
  union { unsigned int i; float f; } x; x.i = u; return x.f;
}
__device__ __forceinline__ unsigned short f2bf(float f) {   // RNE
  union { float f; unsigned int i; } x; x.f = f;
  unsigned int r = x.i + 0x7fffu + ((x.i >> 16) & 1u);
  return (unsigned short)(r >> 16);
}
__device__ __forceinline__ unsigned int pack_bf2(float a, float b) {
  __hip_bfloat162 h = __float22bfloat162_rn(float2{a, b});
  union { __hip_bfloat162 h; unsigned int u; } c; c.h = h;
  return c.u;
}

// frag addr for W[k][n] (128x128), matches gemm_tile's B-frag read
__device__ __forceinline__ int frag_addr(int k, int n) {
  return ((((n >> 4) * 4 + (k >> 5)) * 64 + ((k >> 3) & 3) * 16 + (n & 15)) << 3)
       + (k & 7);
}

// ---------------- prep: counts=0 + W frags + Wc fold ----------------
// blocks 0-15: W1/Wfi frag convert; 16-31: Wc=W2@Wl fold; 32: bc. Grid 33.
__global__ __launch_bounds__(256)
void prep_k(const float* __restrict__ W1, const float* __restrict__ Wfi,
            const float* __restrict__ W2, const float* __restrict__ Wl,
            const float* __restrict__ b2, const float* __restrict__ bl,
            unsigned short* __restrict__ Wbf, float* __restrict__ bc,
            int* __restrict__ counts) {
  int b = blockIdx.x, t = threadIdx.x;
  if (b < 16) {
    const float* W = (b < 8) ? W1 : Wfi;
    unsigned short* out = Wbf + ((b < 8) ? 0 : 16384);
    int base = (b & 7) * 2048 + t * 8;
    float4 f0 = *(const float4*)(W + base);
    float4 f1 = *(const float4*)(W + base + 4);
    float v[8] = {f0.x, f0.y, f0.z, f0.w, f1.x, f1.y, f1.z, f1.w};
#pragma unroll
    for (int u = 0; u < 8; u++) {
      int g = base + u;
      out[frag_addr(g >> 7, g & 127)] = f2bf(v[u]);
    }
  } else if (b < 32) {
    // Wc[k][n..n+3] = sum_j W2[k][j] * Wl[j][n..n+3]
    unsigned short* out = Wbf + 2 * 16384;
    int g0 = (b - 16) * 1024 + t * 4;
    int k = g0 >> 7, n = g0 & 127;
    float4 acc = {0.f, 0.f, 0.f, 0.f};
    for (int j = 0; j < 128; j++) {
      float w2 = W2[k * 128 + j];
      float4 wl = *(const float4*)(Wl + j * 128 + n);
      acc.x += w2 * wl.x; acc.y += w2 * wl.y;
      acc.z += w2 * wl.z; acc.w += w2 * wl.w;
    }
    out[frag_addr(k, n + 0)] = f2bf(acc.x);
    out[frag_addr(k, n + 1)] = f2bf(acc.y);
    out[frag_addr(k, n + 2)] = f2bf(acc.z);
    out[frag_addr(k, n + 3)] = f2bf(acc.w);
  } else {
    if (t < 128) {
      float acc = bl[t];
      for (int k = 0; k < 128; k++) acc += b2[k] * Wl[k * 128 + t];
      bc[t] = acc;
    }
  }
  for (int i = b * 256 + t; i < N_; i += 33 * 256) counts[i] = 0;
}

// ---------------- single-pass WIDE fill (device fn): chunk c, 1 edge/thread ----------------
__device__ __forceinline__ void fill_once(const int* __restrict__ ei,
                                          int* __restrict__ counts,
                                          unsigned short* __restrict__ bucket,
                                          int c) {
  int e = c * EPB + (int)threadIdx.x;
  int d = ei[E_ + e];                    // dst
  int s = ei[e];                         // src
  int pos = atomicAdd(&counts[d], 1);    // device-scope RMW (unique slot)
  if (pos < CAP)
    bucket[(size_t)d * CAP + pos] = (unsigned short)s;   // plain write-back store:
    // combines in local L2; visible to later dispatches via kernel-boundary
    // release/acquire; cross-XCD same-line disjoint-byte writes merge via
    // byte dirty masks on writeback.
}

// ---------------- MFMA GEMM tile (device fn) ----------------
// tile = 64 rows; 4 waves x 16-row stripes; B pre-converted frag-ordered bf16.
// Two-half staging: 16 KB LDS; half-1 global loads overlap half-0 MFMAs.
// C/D: col = lane&15, row = (lane>>4)*4 + reg.
template<bool GATHER, bool ABF16, bool OUTBF16, bool HASBIAS>
__device__ __forceinline__ void gemm_tile(const void* __restrict__ in,
                                          const unsigned short* __restrict__ Wbf,
                                          const float* __restrict__ bias,
                                          void* __restrict__ out_, int tile,
                                          const int* __restrict__ bidx,
                                          const int* __restrict__ nidx,
                                          unsigned short* __restrict__ Bs) {
  int tid  = threadIdx.x;
  int lane = tid & 63;
  int wv   = tid >> 6;
  int m    = lane & 15;
  int q    = lane >> 4;
  int rbase = tile * 64 + wv * 16;
  int r     = rbase + m;

  const short8v* Wv  = (const short8v*)Wbf;   // 2048 vecs (32 KB)
  short8v*       Bsv = (short8v*)Bs;          // 1024 vecs (16 KB)

  short8v w[4];
#pragma unroll
  for (int i = 0; i < 4; i++) w[i] = Wv[tid + i * 256];

  size_t ir;
  if (GATHER) ir = (size_t)bidx[r] * ADJ_ + nidx[r];
  else        ir = (size_t)r;

  short8v af[4];
  if (ABF16) {
    const unsigned short* arow = (const unsigned short*)in + ir * DV;
#pragma unroll
    for (int kc = 0; kc < 4; kc++)
      af[kc] = *(const short8v*)(arow + kc * 32 + q * 8);
  } else {
    const float* arow = (const float*)in + ir * DV;
#pragma unroll
    for (int kc = 0; kc < 4; kc++) {
      const float4* p = (const float4*)(arow + kc * 32 + q * 8);
      float4 f0 = p[0], f1 = p[1];
      union { short8v s; unsigned int u[4]; } t;
      t.u[0] = pack_bf2(f0.x, f0.y);
      t.u[1] = pack_bf2(f0.z, f0.w);
      t.u[2] = pack_bf2(f1.x, f1.y);
      t.u[3] = pack_bf2(f1.z, f1.w);
      af[kc] = t.s;
    }
  }

#pragma unroll
  for (int i = 0; i < 4; i++) Bsv[tid + i * 256] = w[i];
  __syncthreads();

  float4v acc[8];
#pragma unroll
  for (int nb = 0; nb < 8; nb++) acc[nb] = (float4v){0.f, 0.f, 0.f, 0.f};

#pragma unroll
  for (int i = 0; i < 4; i++) w[i] = Wv[1024 + tid + i * 256];

#pragma unroll
  for (int nb = 0; nb < 4; nb++)
#pragma unroll
    for (int kc = 0; kc < 4; kc++) {
      short8v bf = Bsv[(nb * 4 + kc) * 64 + lane];
      acc[nb] = __builtin_amdgcn_mfma_f32_16x16x32_bf16(af[kc], bf, acc[nb], 0, 0, 0);
    }
  __syncthreads();
#pragma unroll
  for (int i = 0; i < 4; i++) Bsv[tid + i * 256] = w[i];
  __syncthreads();
#pragma unroll
  for (int nb = 4; nb < 8; nb++)
#pragma unroll
    for (int kc = 0; kc < 4; kc++) {
      short8v bf = Bsv[((nb - 4) * 4 + kc) * 64 + lane];
      acc[nb] = __builtin_amdgcn_mfma_f32_16x16x32_bf16(af[kc], bf, acc[nb], 0, 0, 0);
    }

#pragma unroll
  for (int nb = 0; nb < 8; nb++) {
    float bvn = HASBIAS ? bias[nb * 16 + m] : 0.f;
    int col = nb * 16 + m;
#pragma unroll
    for (int i = 0; i < 4; i++) {
      int row = rbase + q * 4 + i;
      float v = acc[nb][i] + bvn;
      if (OUTBF16) ((unsigned short*)out_)[(size_t)row * DV + col] = f2bf(v);
      else         ((float*)out_)[(size_t)row * DV + col] = v;
    }
  }
}

// ---------------- K1: fused wide fill + gemm1 + branch0 ----------------
// Period-11 blocks: rem 0..7 -> fill chunk g*8+rem (4096 fills); rem 8..10 ->
// o = g*3+rem-8: o<1000 gemm1, o<1500 br0, else idle. Grid 512*11 = 5632.
__global__ __launch_bounds__(256)
void k1_fused(const int* __restrict__ ei, int* __restrict__ counts,
              unsigned short* __restrict__ bucket,
              const float* __restrict__ x1, const unsigned short* __restrict__ Wbf,
              unsigned int* __restrict__ t_bf,
              const float* __restrict__ x0, const float* __restrict__ bfi,
              float* __restrict__ out0,
              const int* __restrict__ b0, const int* __restrict__ n0i) {
  __shared__ unsigned short Bs[8192];   // 16 KB
  int g = blockIdx.x / 11, rem = blockIdx.x % 11;
  if (rem < 8) { fill_once(ei, counts, bucket, g * 8 + rem); return; }
  int o = g * 3 + rem - 8;
  if (o < 1000)
    gemm_tile<false, false, true, false>(x1, Wbf, nullptr, t_bf, o, nullptr, nullptr, Bs);
  else if (o < 1500)
    gemm_tile<true, false, false, true>(x0, Wbf + 16384, bfi, out0, o - 1000, b0, n0i, Bs);
}

// ---------------- standalone GEMM ----------------
template<bool GATHER, bool ABF16, bool OUTBF16, bool HASBIAS>
__global__ __launch_bounds__(256)
void gemm_k(const void* __restrict__ in, const unsigned short* __restrict__ Wbf,
            const float* __restrict__ bias, void* __restrict__ out_,
            const int* __restrict__ bidx, const int* __restrict__ nidx) {
  __shared__ unsigned short Bs[8192];
  gemm_tile<GATHER, ABF16, OUTBF16, HASBIAS>(in, Wbf, bias, out_, blockIdx.x, bidx, nidx, Bs);
}

// ---------------- aggregation: one wave per row, single <=32-deep exposure ----------------
// SEL=false: row w = node id. SEL=true: row w = output slot, node from (bidx,nidx).
// cnt is wave-uniform; per-i `if (i<cnt)` guards are uniform branches: exactly
// cnt gather loads issue back-to-back before any accumulate.
template<bool OUTBF16, bool SEL>
__global__ __launch_bounds__(256)
void aggregate_k(const unsigned int* __restrict__ x,   // bf16x2 rows [N,64]
                 const int* __restrict__ counts,
                 const unsigned short* __restrict__ bucket,
                 const float* __restrict__ bias, void* __restrict__ out_,
                 const int* __restrict__ bidx, const int* __restrict__ nidx) {
  int w    = (blockIdx.x * 256 + threadIdx.x) >> 6;
  int lane = threadIdx.x & 63;
  int node = SEL ? (bidx[w] * ADJ_ + nidx[w]) : w;
  int cnt = counts[node]; cnt = min(cnt, CAP);
  int mysrc = (int)bucket[(size_t)node * CAP + lane];   // lane l holds slot l

  float2 acc;
  if (bias) { float2 bv = ((const float2*)bias)[lane]; acc.x = bv.x; acc.y = bv.y; }
  else      { acc.x = 0.f; acc.y = 0.f; }

  unsigned int uu[32];
#pragma unroll
  for (int i = 0; i < 32; i++)
    if (i < cnt) {                       // wave-uniform guard
      int s = __shfl(mysrc, i, 64);
      uu[i] = x[(size_t)s * 64 + lane];
    }
#pragma unroll
  for (int i = 0; i < 32; i++)
    if (i < cnt) {
      acc.x += u2f(uu[i] << 16);
      acc.y += u2f(uu[i] & 0xffff0000u);
    }
  for (int d = 32; d < cnt; d++) {       // rare tail
    int s = __shfl(mysrc, d, 64);
    unsigned int u = x[(size_t)s * 64 + lane];
    acc.x += u2f(u << 16);
    acc.y += u2f(u & 0xffff0000u);
  }

  if (OUTBF16) ((unsigned int*)out_)[(size_t)w * 64 + lane] = pack_bf2(acc.x, acc.y);
  else         ((float2*)out_)[(size_t)w * 64 + lane] = acc;
}

extern "C" void kernel_launch(void* const* d_in, const int* in_sizes, int n_in,
                              void* d_out, int out_size, void* d_ws, size_t ws_size,
                              hipStream_t stream) {
  const float* x0  = (const float*)d_in[0];
  const float* x1  = (const float*)d_in[1];
  const int*   ei  = (const int*)  d_in[2];
  const int*   b0  = (const int*)  d_in[3];
  const int*   n0i = (const int*)  d_in[4];
  const int*   b1  = (const int*)  d_in[5];
  const int*   n1i = (const int*)  d_in[6];
  const float* W1  = (const float*)d_in[7];
  const float* bb1 = (const float*)d_in[8];
  const float* W2  = (const float*)d_in[9];
  const float* bb2 = (const float*)d_in[10];
  const float* Wl  = (const float*)d_in[11];
  const float* bl  = (const float*)d_in[12];
  const float* Wfi = (const float*)d_in[13];
  const float* bfi = (const float*)d_in[14];
  float* out = (float*)d_out;

  // ws: t_bf 16MB (sel_bf aliases it) | h_bf 16MB | counts 0.25MB | bucket 8MB
  //     | Wbf 96KB | bc 512B   (total ~40.4MB)
  unsigned int*   t_bf   = (unsigned int*)d_ws;
  unsigned int*   sel_bf = t_bf;                        // alias: t1 dead after agg1
  unsigned int*   h_bf   = t_bf + (size_t)N_ * 64;
  int*            counts = (int*)(h_bf + (size_t)N_ * 64);
  unsigned short* bucket = (unsigned short*)(counts + N_);
  unsigned short* Wbf    = bucket + (size_t)N_ * CAP;
  float*          bc     = (float*)(Wbf + 3 * 16384);

  // prep: counts=0, W1/Wfi frag, Wc=W2@Wl frag, bc=b2@Wl+bl
  prep_k<<<33, 256, 0, stream>>>(W1, Wfi, W2, Wl, bb2, bl, Wbf, bc, counts);

  // K1: wide single-pass fill ∪ t1=x1@W1 ∪ out0=gather(x0)@Wfi+bfi
  k1_fused<<<5632, 256, 0, stream>>>(ei, counts, bucket, x1, Wbf, t_bf,
                                     x0, bfi, out, b0, n0i);

  // h1 = A@t1 + b1  (bf16 out)
  aggregate_k<true, false><<<N_ / 4, 256, 0, stream>>>(t_bf, counts, bucket,
                                                       bb1, h_bf, nullptr, nullptr);
  // sel[m] = A-row(node(m)) @ h1  (bf16 out, bias folded into bc)
  aggregate_k<true, true><<<M_ / 4, 256, 0, stream>>>(h_bf, counts, bucket,
                                                      nullptr, sel_bf, b1, n1i);
  // out1 = sel@Wc + bc  (f32 out)   [Wc = W2@Wl, bc = b2@Wl + bl]
  gemm_k<false, true, false, true><<<M_ / 64, 256, 0, stream>>>(sel_bf, Wbf + 2 * 16384,
                                                                bc, out + (size_t)M_ * DV,
                                                                nullptr, nullptr);
}